// Round 4
// baseline (1040.179 us; speedup 1.0000x reference)
//
#include <hip/hip_runtime.h>

// TransformerBlock on MI355X (gfx950). External dtype: FP32 (per reference).
// Internals bf16 for MFMA GEMMs, fp32 accumulate/epilogues.
//   transpose_k: W fp32 [K,N] -> bf16 [N,K]
//   ln_dual:     nx = LN(x,attn_ln), f = LN(x,ffn_ln)   (fp32 in, bf16 out)
//   gemm<0>:     qkv = nx @ Wqkv + b                    (bf16 out)
//   qk_rope:     RMSNorm + RoPE(first 32 dims) + V rearrange (bf16)
//   attn:        sliding-window(256) causal flash attention (bf16, VALU)
//   gemm<2>:     tmid = gelu_exact(f @ W1 + b1)         (bf16 out)
//   gemm<1>:     h = x + y @ Wo + b     -> stored fp32 in d_out
//   gemm<1>:     out = h + tmid @ W2 + b2               (fp32, in-place res)
//
// R3 post-mortem: persistent NaN traced to reading fp32 inputs as bf16
// (reference dtypes are float32; "(bf16" in harness message is template
// text). This round: fp32 I/O boundary, bf16 MFMA internals.

typedef unsigned short u16;
typedef unsigned int   u32;
typedef __bf16 bf16x8 __attribute__((ext_vector_type(8)));
typedef float  f32x4  __attribute__((ext_vector_type(4)));

#define B_    2
#define S_    2048
#define D_    2048
#define H_    16
#define HD_   128
#define FF_   4096
#define WIN_  256
#define EPS_  1e-5f
#define SCALE_ 0.08838834764831845f  // 1/sqrt(128)

__device__ __forceinline__ float b2f(u16 u) {
    return __uint_as_float(((u32)u) << 16);
}
__device__ __forceinline__ u16 f2b(float f) {
    u32 u = __float_as_uint(f);
    u32 r = (u + 0x7fffu + ((u >> 16) & 1u)) >> 16;  // RNE
    return (u16)r;
}
__device__ __forceinline__ float wave_sum(float v) {
#pragma unroll
    for (int o = 32; o > 0; o >>= 1) v += __shfl_xor(v, o);
    return v;
}
__device__ __forceinline__ float wave_max(float v) {
#pragma unroll
    for (int o = 32; o > 0; o >>= 1) v = fmaxf(v, __shfl_xor(v, o));
    return v;
}

// -------- weight transpose + cast: in fp32 [R][C] -> out bf16 [C][R] -------
__global__ __launch_bounds__(256) void transpose_k(const float* __restrict__ in,
                                                   u16* __restrict__ out,
                                                   int R, int C) {
    __shared__ float tile[32][33];
    int tx = threadIdx.x & 31, ty = threadIdx.x >> 5;  // ty 0..7
    int c0 = blockIdx.x * 32, r0 = blockIdx.y * 32;
#pragma unroll
    for (int i = 0; i < 32; i += 8)
        tile[ty + i][tx] = in[(size_t)(r0 + ty + i) * C + c0 + tx];
    __syncthreads();
#pragma unroll
    for (int i = 0; i < 32; i += 8)
        out[(size_t)(c0 + ty + i) * R + r0 + tx] = f2b(tile[tx][ty + i]);
}

// ---------- dual LayerNorm: fp32 x -> bf16 nx, f (one pass) ----------------
__global__ __launch_bounds__(256) void ln_dual(const float* __restrict__ x,
        const float* __restrict__ aw, const float* __restrict__ ab,
        const float* __restrict__ fw, const float* __restrict__ fb,
        u16* __restrict__ nx, u16* __restrict__ f) {
    int row = blockIdx.x;                // 0..B*S-1
    const float* xr = x + (size_t)row * D_;
    int base = threadIdx.x * 8;
    float4 xa = *(const float4*)&xr[base];
    float4 xb = *(const float4*)&xr[base + 4];
    float xv[8] = {xa.x, xa.y, xa.z, xa.w, xb.x, xb.y, xb.z, xb.w};
    float s = 0.f, s2 = 0.f;
#pragma unroll
    for (int i = 0; i < 8; ++i) { s += xv[i]; s2 += xv[i] * xv[i]; }
    s = wave_sum(s); s2 = wave_sum(s2);
    __shared__ float r1[4], r2[4];
    int w = threadIdx.x >> 6;
    if ((threadIdx.x & 63) == 0) { r1[w] = s; r2[w] = s2; }
    __syncthreads();
    float ts  = r1[0] + r1[1] + r1[2] + r1[3];
    float ts2 = r2[0] + r2[1] + r2[2] + r2[3];
    float mean = ts * (1.f / D_);
    float var  = ts2 * (1.f / D_) - mean * mean;
    float inv  = rsqrtf(var + EPS_);
    float4 wa0 = *(const float4*)&aw[base], wa1 = *(const float4*)&aw[base + 4];
    float4 ba0 = *(const float4*)&ab[base], ba1 = *(const float4*)&ab[base + 4];
    float4 wf0 = *(const float4*)&fw[base], wf1 = *(const float4*)&fw[base + 4];
    float4 bf0 = *(const float4*)&fb[base], bf1 = *(const float4*)&fb[base + 4];
    float wav[8] = {wa0.x, wa0.y, wa0.z, wa0.w, wa1.x, wa1.y, wa1.z, wa1.w};
    float bav[8] = {ba0.x, ba0.y, ba0.z, ba0.w, ba1.x, ba1.y, ba1.z, ba1.w};
    float wfv[8] = {wf0.x, wf0.y, wf0.z, wf0.w, wf1.x, wf1.y, wf1.z, wf1.w};
    float bfv[8] = {bf0.x, bf0.y, bf0.z, bf0.w, bf1.x, bf1.y, bf1.z, bf1.w};
    union { uint4 v; u16 s[8]; } o1, o2;
#pragma unroll
    for (int i = 0; i < 8; ++i) {
        float t = (xv[i] - mean) * inv;
        o1.s[i] = f2b(t * wav[i] + bav[i]);
        o2.s[i] = f2b(t * wfv[i] + bfv[i]);
    }
    *(uint4*)&nx[(size_t)row * D_ + base] = o1.v;
    *(uint4*)&f [(size_t)row * D_ + base] = o2.v;
}

// ---------------- MFMA GEMM: C[M,N] = A[M,K] @ BT[N,K]^T + bias ------------
// A, BT bf16. bias fp32.
// EPI 0: bf16 out.  EPI 1: fp32 out, += fp32 residual.  EPI 2: bf16 out, GELU.
template <int EPI>
__global__ __launch_bounds__(256, 2) void gemm_bt(
        const u16* __restrict__ A, const u16* __restrict__ BT,
        const float* __restrict__ bias, const float* __restrict__ res,
        void* __restrict__ Cv, int M, int N, int K) {
    __shared__ __align__(16) u16 As[128][40];
    __shared__ __align__(16) u16 Bs[128][40];
    int m0 = blockIdx.y * 128, n0 = blockIdx.x * 128;
    int w = threadIdx.x >> 6, lane = threadIdx.x & 63;
    int wm = (w >> 1) * 64, wn = (w & 1) * 64;
    int row16 = lane & 15, quad = lane >> 4;
    int tr = threadIdx.x >> 2, tc = (threadIdx.x & 3) * 8;
    f32x4 acc[4][4] = {};
    for (int k0 = 0; k0 < K; k0 += 32) {
        __syncthreads();
        *(uint4*)&As[tr][tc]      = *(const uint4*)&A [(size_t)(m0 + tr)      * K + k0 + tc];
        *(uint4*)&As[tr + 64][tc] = *(const uint4*)&A [(size_t)(m0 + tr + 64) * K + k0 + tc];
        *(uint4*)&Bs[tr][tc]      = *(const uint4*)&BT[(size_t)(n0 + tr)      * K + k0 + tc];
        *(uint4*)&Bs[tr + 64][tc] = *(const uint4*)&BT[(size_t)(n0 + tr + 64) * K + k0 + tc];
        __syncthreads();
        bf16x8 af[4], bfr[4];
#pragma unroll
        for (int i = 0; i < 4; ++i) {
            af[i]  = *(const bf16x8*)&As[wm + i * 16 + row16][quad * 8];
            bfr[i] = *(const bf16x8*)&Bs[wn + i * 16 + row16][quad * 8];
        }
#pragma unroll
        for (int mi = 0; mi < 4; ++mi)
#pragma unroll
            for (int ni = 0; ni < 4; ++ni)
                acc[mi][ni] = __builtin_amdgcn_mfma_f32_16x16x32_bf16(
                        af[mi], bfr[ni], acc[mi][ni], 0, 0, 0);
    }
#pragma unroll
    for (int mi = 0; mi < 4; ++mi) {
#pragma unroll
        for (int ni = 0; ni < 4; ++ni) {
            int gcol = n0 + wn + ni * 16 + row16;
            float bv = bias[gcol];
#pragma unroll
            for (int i = 0; i < 4; ++i) {
                int grow = m0 + wm + mi * 16 + quad * 4 + i;
                float vv = acc[mi][ni][i] + bv;
                if (EPI == 1) {
                    vv += res[(size_t)grow * N + gcol];
                    ((float*)Cv)[(size_t)grow * N + gcol] = vv;
                } else {
                    if (EPI == 2)
                        vv = vv * 0.5f * (1.0f + erff(vv * 0.70710678118654752f));
                    ((u16*)Cv)[(size_t)grow * N + gcol] = f2b(vv);
                }
            }
        }
    }
}

// ---------------- QK RMSNorm + partial RoPE + V rearrange ------------------
// One wave per (b,s,h). Lane l holds dims l and l+64. qkv bf16; weights fp32.
__global__ __launch_bounds__(256) void qk_rope(const u16* __restrict__ qkv,
        const float* __restrict__ qn_w, const float* __restrict__ kn_w,
        const float* __restrict__ freqs,
        u16* __restrict__ q, u16* __restrict__ k, u16* __restrict__ v) {
    int w = threadIdx.x >> 6, lane = threadIdx.x & 63;
    int unit = blockIdx.x * 4 + w;           // b*S*H + s*H + h
    int h = unit & (H_ - 1);
    int s = (unit >> 4) & (S_ - 1);
    int b = unit >> 15;
    size_t inbase  = (size_t)(b * S_ + s) * (3 * D_) + h * HD_;
    size_t outbase = ((size_t)((b * H_ + h) * S_) + s) * HD_;
    int t = (lane & 31) >> 1;
    float c  = freqs[(s * 16 + t) * 2];
    float sn = freqs[(s * 16 + t) * 2 + 1];
#pragma unroll
    for (int part = 0; part < 2; ++part) {   // 0: q, 1: k
        const float* nw = part ? kn_w : qn_w;
        size_t ib = inbase + (size_t)part * D_;
        float a0 = b2f(qkv[ib + lane]);
        float a1 = b2f(qkv[ib + 64 + lane]);
        float ss = wave_sum(a0 * a0 + a1 * a1);
        float inv = rsqrtf(ss * (1.f / HD_) + EPS_);
        float n0 = a0 * inv * nw[lane];
        float n1 = a1 * inv * nw[64 + lane];
        float x0 = __shfl(n0, t);
        float x1 = __shfl(n0, t + 16);
        float roped = (lane & 1) ? (x1 * c + x0 * sn) : (x0 * c - x1 * sn);
        float out0 = (lane < 32) ? roped : n0;
        u16* dst = part ? k : q;
        dst[outbase + lane]      = f2b(out0);
        dst[outbase + 64 + lane] = f2b(n1);
    }
    v[outbase + lane]      = qkv[inbase + 2 * D_ + lane];
    v[outbase + 64 + lane] = qkv[inbase + 2 * D_ + 64 + lane];
}

// ---------------- sliding-window causal attention --------------------------
// Block = 4 waves = 4 consecutive queries of one (b,h). K/V staged in LDS in
// 64-key tiles; online softmax; lane j <-> key j for QK, lane d <-> dim pair
// (2d, 2d+1) for PV/output. All bf16 buffers.
__global__ __launch_bounds__(256) void attn_kernel(const u16* __restrict__ q,
        const u16* __restrict__ k, const u16* __restrict__ v,
        u16* __restrict__ y) {
    __shared__ __align__(16) u16 Ks[64][132];   // 264B rows (8B-aligned)
    __shared__ __align__(16) u16 Vs[64][132];
    __shared__ float Qs[4][128];
    int qg = blockIdx.x & (S_ / 4 - 1);   // 0..511
    int bh = blockIdx.x >> 9;
    int qbase = qg * 4;
    size_t kvbase = (size_t)bh * S_ * HD_;
    int w = threadIdx.x >> 6, lane = threadIdx.x & 63;
    {
        size_t qb_ = kvbase + (size_t)(qbase + w) * HD_;
        Qs[w][lane]      = b2f(q[qb_ + lane])      * SCALE_;
        Qs[w][64 + lane] = b2f(q[qb_ + 64 + lane]) * SCALE_;
    }
    int qi = qbase + w;
    float m = -1e30f, lsum = 0.f, o0 = 0.f, o1 = 0.f;
    int jlo = qbase - (WIN_ - 1); if (jlo < 0) jlo = 0;
    int t0 = jlo >> 6, t1 = (qbase + 3) >> 6;
    int sj = threadIdx.x >> 2;            // staging: key row 0..63
    int sc = (threadIdx.x & 3) * 32;      // staging: dim start (32 u16 = 64B)
    for (int kt = t0; kt <= t1; ++kt) {
        __syncthreads();
        {
            size_t gb = kvbase + (size_t)(kt * 64 + sj) * HD_ + sc;
#pragma unroll
            for (int uu = 0; uu < 4; ++uu) {   // 4 x uint4 = 32 u16 = 64B
                uint4 kk = *(const uint4*)&k[gb + uu * 8];
                uint4 vv = *(const uint4*)&v[gb + uu * 8];
                *(uint2*)&Ks[sj][sc + uu * 8]     = make_uint2(kk.x, kk.y);
                *(uint2*)&Ks[sj][sc + uu * 8 + 4] = make_uint2(kk.z, kk.w);
                *(uint2*)&Vs[sj][sc + uu * 8]     = make_uint2(vv.x, vv.y);
                *(uint2*)&Vs[sj][sc + uu * 8 + 4] = make_uint2(vv.z, vv.w);
            }
        }
        __syncthreads();
        bool overlap = (kt * 64 <= qi) && (kt * 64 + 63 > qi - WIN_);
        if (overlap) {
            int jg = kt * 64 + lane;
            bool valid = (jg <= qi) && (qi - jg < WIN_);
            float accd = 0.f;
            const u32* krow = (const u32*)&Ks[lane][0];
            const float* qrow = &Qs[w][0];
#pragma unroll 16
            for (int i = 0; i < 64; ++i) {
                u32 kp = krow[i];
                accd += qrow[2 * i]     * __uint_as_float(kp << 16);
                accd += qrow[2 * i + 1] * __uint_as_float(kp & 0xffff0000u);
            }
            float sv = valid ? accd : -1e30f;
            float tm = wave_max(sv);
            float mnew = fmaxf(m, tm);
            float alpha = __expf(m - mnew);
            float p = valid ? __expf(sv - mnew) : 0.f;
            float psum = wave_sum(p);
            lsum = lsum * alpha + psum;
            o0 *= alpha; o1 *= alpha;
            u32 pbits = __float_as_uint(p);
#pragma unroll 8
            for (int j = 0; j < 64; ++j) {
                float pj = __uint_as_float(__builtin_amdgcn_readlane(pbits, j));
                u32 vp = *(const u32*)&Vs[j][2 * lane];
                o0 += pj * __uint_as_float(vp << 16);
                o1 += pj * __uint_as_float(vp & 0xffff0000u);
            }
            m = mnew;
        }
    }
    float invl = 1.f / lsum;
    int b = bh >> 4, hh = bh & 15;
    size_t ob = (size_t)(b * S_ + qi) * D_ + hh * HD_;
    u32 pw = (u32)f2b(o0 * invl) | ((u32)f2b(o1 * invl) << 16);
    *(u32*)&y[ob + 2 * lane] = pw;
}

// ---------------------------- host orchestration ---------------------------
extern "C" void kernel_launch(void* const* d_in, const int* in_sizes, int n_in,
                              void* d_out, int out_size, void* d_ws, size_t ws_size,
                              hipStream_t stream) {
    const float* x      = (const float*)d_in[0];
    const float* freqs  = (const float*)d_in[1];
    // d_in[2] = mask (unused; computed analytically)
    const float* wqkv_w = (const float*)d_in[3];
    const float* wqkv_b = (const float*)d_in[4];
    const float* wo_w   = (const float*)d_in[5];
    const float* wo_b   = (const float*)d_in[6];
    const float* qn_w   = (const float*)d_in[7];
    const float* kn_w   = (const float*)d_in[8];
    const float* aln_w  = (const float*)d_in[9];
    const float* aln_b  = (const float*)d_in[10];
    const float* fln_w  = (const float*)d_in[11];
    const float* fln_b  = (const float*)d_in[12];
    const float* w1_w   = (const float*)d_in[13];
    const float* w1_b   = (const float*)d_in[14];
    const float* w2_w   = (const float*)d_in[15];
    const float* w2_b   = (const float*)d_in[16];
    float* out = (float*)d_out;

    char* ws = (char*)d_ws;
    size_t off = 0;
    auto alloc = [&](size_t bytes) { char* p = ws + off; off += (bytes + 255) & ~(size_t)255; return (u16*)p; };
    const size_t E = sizeof(u16);
    u16* wt_qkv = alloc((size_t)D_ * 3 * D_ * E);       // bf16 [6144,2048]
    u16* wt_wo  = alloc((size_t)D_ * D_ * E);           // bf16 [2048,2048]
    u16* wt_w1  = alloc((size_t)D_ * FF_ * E);          // bf16 [4096,2048]
    u16* wt_w2  = alloc((size_t)FF_ * D_ * E);          // bf16 [2048,4096]
    u16* nx     = alloc((size_t)B_ * S_ * D_ * E);      // bf16; reused as y
    u16* f      = alloc((size_t)B_ * S_ * D_ * E);      // bf16
    u16* qkv    = alloc((size_t)B_ * S_ * 3 * D_ * E);  // bf16; reused as tmid
    u16* qb     = alloc((size_t)B_ * S_ * D_ * E);      // bf16
    u16* kb     = alloc((size_t)B_ * S_ * D_ * E);      // bf16
    u16* vb     = alloc((size_t)B_ * S_ * D_ * E);      // bf16
    u16* y    = nx;    // nx consumed by QKV GEMM before attention writes y
    u16* tmid = qkv;   // qkv consumed by qk_rope before FFN1 writes tmid
    float* h  = out;   // h lives in d_out; final GEMM reads res=h, writes out

    // Tripwire: if ws too small, do nothing -> finite err (= max|ref|).
    if (off > ws_size) return;

    const int M = B_ * S_;  // 4096

    transpose_k<<<dim3(3 * D_ / 32, D_ / 32), 256, 0, stream>>>(wqkv_w, wt_qkv, D_, 3 * D_);
    transpose_k<<<dim3(D_ / 32, D_ / 32),     256, 0, stream>>>(wo_w,   wt_wo,  D_, D_);
    transpose_k<<<dim3(FF_ / 32, D_ / 32),    256, 0, stream>>>(w1_w,   wt_w1,  D_, FF_);
    transpose_k<<<dim3(D_ / 32, FF_ / 32),    256, 0, stream>>>(w2_w,   wt_w2,  FF_, D_);

    ln_dual<<<M, 256, 0, stream>>>(x, aln_w, aln_b, fln_w, fln_b, nx, f);

    gemm_bt<0><<<dim3(3 * D_ / 128, M / 128), 256, 0, stream>>>(nx, wt_qkv, wqkv_b, nullptr, qkv, M, 3 * D_, D_);

    qk_rope<<<B_ * S_ * H_ / 4, 256, 0, stream>>>(qkv, qn_w, kn_w, freqs, qb, kb, vb);

    attn_kernel<<<B_ * H_ * (S_ / 4), 256, 0, stream>>>(qb, kb, vb, y);

    // FFN1 first so f is consumed before anything else; then WO writes h=out.
    gemm_bt<2><<<dim3(FF_ / 128, M / 128), 256, 0, stream>>>(f, wt_w1, w1_b, nullptr, tmid, M, FF_, D_);

    gemm_bt<1><<<dim3(D_ / 128, M / 128), 256, 0, stream>>>(y, wt_wo, wo_b, x, h, M, D_, D_);

    gemm_bt<1><<<dim3(D_ / 128, M / 128), 256, 0, stream>>>(tmid, wt_w2, w2_b, h, out, M, D_, FF_);
}

// Round 5
// 714.452 us; speedup vs baseline: 1.4559x; 1.4559x over previous
//
#include <hip/hip_runtime.h>

// TransformerBlock on MI355X (gfx950). External dtype: FP32. Internals bf16.
//   transpose_k: W fp32 [K,N] -> bf16 [N,K]
//   ln_dual:     nx = LN(x,attn_ln), f = LN(x,ffn_ln)   (fp32 in, bf16 out)
//   gemm<0>:     qkv = nx @ Wqkv + b                    (bf16 out)
//   qk_rope:     RMSNorm + RoPE(first 32 dims) on q,k   (bf16)
//   v_transpose: V part of qkv -> vt [b][h][dim][key]   (bf16)
//   attn_mfma:   sliding-window(256) causal flash attention, MFMA
//   gemm<2>:     tmid = gelu_exact(f @ W1 + b1)         (bf16 out)
//   gemm<1>:     h = x + y @ Wo + b                     (fp32, in d_out)
//   gemm<1>:     out = h + tmid @ W2 + b2               (fp32)
//
// R4 -> R5: attention rewritten from scalar-VALU (455us, MfmaUtil=0,
// VALUBusy=82%) to MFMA flash: wave = 16-query M-tile, 64-key LDS tiles,
// QK^T and PV on mfma_f32_16x16x32_bf16, P transits LDS (C-layout ->
// A-layout), V pre-transposed to [dim][key] so PV B-frags are contiguous-key.

typedef unsigned short u16;
typedef unsigned int   u32;
typedef __bf16 bf16x8 __attribute__((ext_vector_type(8)));
typedef float  f32x4  __attribute__((ext_vector_type(4)));

#define B_    2
#define S_    2048
#define D_    2048
#define H_    16
#define HD_   128
#define FF_   4096
#define WIN_  256
#define EPS_  1e-5f
#define SCALE_ 0.08838834764831845f  // 1/sqrt(128)

__device__ __forceinline__ float b2f(u16 u) {
    return __uint_as_float(((u32)u) << 16);
}
__device__ __forceinline__ u16 f2b(float f) {
    u32 u = __float_as_uint(f);
    u32 r = (u + 0x7fffu + ((u >> 16) & 1u)) >> 16;  // RNE
    return (u16)r;
}
__device__ __forceinline__ float wave_sum(float v) {
#pragma unroll
    for (int o = 32; o > 0; o >>= 1) v += __shfl_xor(v, o);
    return v;
}

// -------- weight transpose + cast: in fp32 [R][C] -> out bf16 [C][R] -------
__global__ __launch_bounds__(256) void transpose_k(const float* __restrict__ in,
                                                   u16* __restrict__ out,
                                                   int R, int C) {
    __shared__ float tile[32][33];
    int tx = threadIdx.x & 31, ty = threadIdx.x >> 5;  // ty 0..7
    int c0 = blockIdx.x * 32, r0 = blockIdx.y * 32;
#pragma unroll
    for (int i = 0; i < 32; i += 8)
        tile[ty + i][tx] = in[(size_t)(r0 + ty + i) * C + c0 + tx];
    __syncthreads();
#pragma unroll
    for (int i = 0; i < 32; i += 8)
        out[(size_t)(c0 + ty + i) * R + r0 + tx] = f2b(tile[tx][ty + i]);
}

// ---------- dual LayerNorm: fp32 x -> bf16 nx, f (one pass) ----------------
__global__ __launch_bounds__(256) void ln_dual(const float* __restrict__ x,
        const float* __restrict__ aw, const float* __restrict__ ab,
        const float* __restrict__ fw, const float* __restrict__ fb,
        u16* __restrict__ nx, u16* __restrict__ f) {
    int row = blockIdx.x;                // 0..B*S-1
    const float* xr = x + (size_t)row * D_;
    int base = threadIdx.x * 8;
    float4 xa = *(const float4*)&xr[base];
    float4 xb = *(const float4*)&xr[base + 4];
    float xv[8] = {xa.x, xa.y, xa.z, xa.w, xb.x, xb.y, xb.z, xb.w};
    float s = 0.f, s2 = 0.f;
#pragma unroll
    for (int i = 0; i < 8; ++i) { s += xv[i]; s2 += xv[i] * xv[i]; }
    s = wave_sum(s); s2 = wave_sum(s2);
    __shared__ float r1[4], r2[4];
    int w = threadIdx.x >> 6;
    if ((threadIdx.x & 63) == 0) { r1[w] = s; r2[w] = s2; }
    __syncthreads();
    float ts  = r1[0] + r1[1] + r1[2] + r1[3];
    float ts2 = r2[0] + r2[1] + r2[2] + r2[3];
    float mean = ts * (1.f / D_);
    float var  = ts2 * (1.f / D_) - mean * mean;
    float inv  = rsqrtf(var + EPS_);
    float4 wa0 = *(const float4*)&aw[base], wa1 = *(const float4*)&aw[base + 4];
    float4 ba0 = *(const float4*)&ab[base], ba1 = *(const float4*)&ab[base + 4];
    float4 wf0 = *(const float4*)&fw[base], wf1 = *(const float4*)&fw[base + 4];
    float4 bf0 = *(const float4*)&fb[base], bf1 = *(const float4*)&fb[base + 4];
    float wav[8] = {wa0.x, wa0.y, wa0.z, wa0.w, wa1.x, wa1.y, wa1.z, wa1.w};
    float bav[8] = {ba0.x, ba0.y, ba0.z, ba0.w, ba1.x, ba1.y, ba1.z, ba1.w};
    float wfv[8] = {wf0.x, wf0.y, wf0.z, wf0.w, wf1.x, wf1.y, wf1.z, wf1.w};
    float bfv[8] = {bf0.x, bf0.y, bf0.z, bf0.w, bf1.x, bf1.y, bf1.z, bf1.w};
    union { uint4 v; u16 s[8]; } o1, o2;
#pragma unroll
    for (int i = 0; i < 8; ++i) {
        float t = (xv[i] - mean) * inv;
        o1.s[i] = f2b(t * wav[i] + bav[i]);
        o2.s[i] = f2b(t * wfv[i] + bfv[i]);
    }
    *(uint4*)&nx[(size_t)row * D_ + base] = o1.v;
    *(uint4*)&f [(size_t)row * D_ + base] = o2.v;
}

// ---------------- MFMA GEMM: C[M,N] = A[M,K] @ BT[N,K]^T + bias ------------
// A, BT bf16. bias fp32.
// EPI 0: bf16 out.  EPI 1: fp32 out, += fp32 residual.  EPI 2: bf16 out, GELU.
template <int EPI>
__global__ __launch_bounds__(256, 2) void gemm_bt(
        const u16* __restrict__ A, const u16* __restrict__ BT,
        const float* __restrict__ bias, const float* __restrict__ res,
        void* __restrict__ Cv, int M, int N, int K) {
    __shared__ __align__(16) u16 As[128][40];
    __shared__ __align__(16) u16 Bs[128][40];
    int m0 = blockIdx.y * 128, n0 = blockIdx.x * 128;
    int w = threadIdx.x >> 6, lane = threadIdx.x & 63;
    int wm = (w >> 1) * 64, wn = (w & 1) * 64;
    int row16 = lane & 15, quad = lane >> 4;
    int tr = threadIdx.x >> 2, tc = (threadIdx.x & 3) * 8;
    f32x4 acc[4][4] = {};
    for (int k0 = 0; k0 < K; k0 += 32) {
        __syncthreads();
        *(uint4*)&As[tr][tc]      = *(const uint4*)&A [(size_t)(m0 + tr)      * K + k0 + tc];
        *(uint4*)&As[tr + 64][tc] = *(const uint4*)&A [(size_t)(m0 + tr + 64) * K + k0 + tc];
        *(uint4*)&Bs[tr][tc]      = *(const uint4*)&BT[(size_t)(n0 + tr)      * K + k0 + tc];
        *(uint4*)&Bs[tr + 64][tc] = *(const uint4*)&BT[(size_t)(n0 + tr + 64) * K + k0 + tc];
        __syncthreads();
        bf16x8 af[4], bfr[4];
#pragma unroll
        for (int i = 0; i < 4; ++i) {
            af[i]  = *(const bf16x8*)&As[wm + i * 16 + row16][quad * 8];
            bfr[i] = *(const bf16x8*)&Bs[wn + i * 16 + row16][quad * 8];
        }
#pragma unroll
        for (int mi = 0; mi < 4; ++mi)
#pragma unroll
            for (int ni = 0; ni < 4; ++ni)
                acc[mi][ni] = __builtin_amdgcn_mfma_f32_16x16x32_bf16(
                        af[mi], bfr[ni], acc[mi][ni], 0, 0, 0);
    }
#pragma unroll
    for (int mi = 0; mi < 4; ++mi) {
#pragma unroll
        for (int ni = 0; ni < 4; ++ni) {
            int gcol = n0 + wn + ni * 16 + row16;
            float bv = bias[gcol];
#pragma unroll
            for (int i = 0; i < 4; ++i) {
                int grow = m0 + wm + mi * 16 + quad * 4 + i;
                float vv = acc[mi][ni][i] + bv;
                if (EPI == 1) {
                    vv += res[(size_t)grow * N + gcol];
                    ((float*)Cv)[(size_t)grow * N + gcol] = vv;
                } else {
                    if (EPI == 2)
                        vv = vv * 0.5f * (1.0f + erff(vv * 0.70710678118654752f));
                    ((u16*)Cv)[(size_t)grow * N + gcol] = f2b(vv);
                }
            }
        }
    }
}

// ---------------- QK RMSNorm + partial RoPE (q,k only) ---------------------
// One wave per (b,s,h). Lane l holds dims l and l+64.
__global__ __launch_bounds__(256) void qk_rope(const u16* __restrict__ qkv,
        const float* __restrict__ qn_w, const float* __restrict__ kn_w,
        const float* __restrict__ freqs,
        u16* __restrict__ q, u16* __restrict__ k) {
    int w = threadIdx.x >> 6, lane = threadIdx.x & 63;
    int unit = blockIdx.x * 4 + w;           // b*S*H + s*H + h
    int h = unit & (H_ - 1);
    int s = (unit >> 4) & (S_ - 1);
    int b = unit >> 15;
    size_t inbase  = (size_t)(b * S_ + s) * (3 * D_) + h * HD_;
    size_t outbase = ((size_t)((b * H_ + h) * S_) + s) * HD_;
    int t = (lane & 31) >> 1;
    float c  = freqs[(s * 16 + t) * 2];
    float sn = freqs[(s * 16 + t) * 2 + 1];
#pragma unroll
    for (int part = 0; part < 2; ++part) {   // 0: q, 1: k
        const float* nw = part ? kn_w : qn_w;
        size_t ib = inbase + (size_t)part * D_;
        float a0 = b2f(qkv[ib + lane]);
        float a1 = b2f(qkv[ib + 64 + lane]);
        float ss = wave_sum(a0 * a0 + a1 * a1);
        float inv = rsqrtf(ss * (1.f / HD_) + EPS_);
        float n0 = a0 * inv * nw[lane];
        float n1 = a1 * inv * nw[64 + lane];
        float x0 = __shfl(n0, t);
        float x1 = __shfl(n0, t + 16);
        float roped = (lane & 1) ? (x1 * c + x0 * sn) : (x0 * c - x1 * sn);
        float out0 = (lane < 32) ? roped : n0;
        u16* dst = part ? k : q;
        dst[outbase + lane]      = f2b(out0);
        dst[outbase + 64 + lane] = f2b(n1);
    }
}

// -------- V transpose: qkv V-part [b][s][h][d] -> vt [b][h][d][s] ----------
// u32 granularity (2 bf16). Tile: 64 s x 32 d per block.
__global__ __launch_bounds__(256) void v_transpose(const u32* __restrict__ qkv32,
                                                   u32* __restrict__ vt32) {
    __shared__ u32 tile[64][17];
    int bh = blockIdx.z; int b = bh >> 4, h = bh & 15;
    int s0 = blockIdx.x * 64, d0 = blockIdx.y * 32;
    int tid = threadIdx.x;
    int rr = tid >> 4, cc = tid & 15;          // rr 0..15, cc 0..15 (u32 cols)
#pragma unroll
    for (int i = 0; i < 4; ++i) {
        int s = s0 + rr + i * 16;
        tile[rr + i * 16][cc] =
            qkv32[(size_t)(b * S_ + s) * (3 * D_ / 2) + (2 * D_ + h * HD_ + d0) / 2 + cc];
    }
    __syncthreads();
    int dr = tid & 31, sc = tid >> 5;          // dr 0..31, sc 0..7
#pragma unroll
    for (int i = 0; i < 4; ++i) {
        int s2 = sc + i * 8;                   // s-pair index 0..31
        u32 w0 = tile[2 * s2][dr >> 1];
        u32 w1 = tile[2 * s2 + 1][dr >> 1];
        u32 h0 = (dr & 1) ? (w0 >> 16) : (w0 & 0xffffu);
        u32 h1 = (dr & 1) ? (w1 >> 16) : (w1 & 0xffffu);
        vt32[((size_t)bh * HD_ + d0 + dr) * (S_ / 2) + (s0 >> 1) + s2] = h0 | (h1 << 16);
    }
}

// ---------------- MFMA sliding-window causal flash attention ---------------
// Block = 4 waves; wave w owns 16 queries q0w..q0w+15 of one (b,h).
// K-tiles of 64 keys staged in LDS (K row-major [key][dim], V^T [dim][key]).
// QK^T: A=Q(reg), B=K rows. Softmax in C-layout. P -> LDS -> A-layout. PV:
// B=V^T rows. All tiles t in [max(0,g-4), g] are processed by all 4 waves
// (identical range -> uniform barriers); masking handles edges.
__global__ __launch_bounds__(256) void attn_mfma(
        const u16* __restrict__ q, const u16* __restrict__ k,
        const u16* __restrict__ vt, u16* __restrict__ y) {
    __shared__ __align__(16) u16 Ks [64][136];   // 272B rows: 68-word stride
    __shared__ __align__(16) u16 Vts[128][72];   // 144B rows: 36-word stride
    __shared__ __align__(16) u16 Ps [4][16][72];
    int g  = blockIdx.x & (S_ / 64 - 1);   // 0..31
    int bh = blockIdx.x >> 5;              // 0..31
    int qbase = g * 64;
    size_t kvbase = (size_t)bh * S_ * HD_;
    size_t vtbase = (size_t)bh * HD_ * S_;
    int w = threadIdx.x >> 6, lane = threadIdx.x & 63;
    int col16 = lane & 15, quad = lane >> 4;
    int q0w = qbase + w * 16;
    bf16x8 af[4];
#pragma unroll
    for (int kb = 0; kb < 4; ++kb)
        af[kb] = *(const bf16x8*)&q[kvbase + (size_t)(q0w + col16) * HD_ + kb * 32 + quad * 8];
    f32x4 oacc[8] = {};
    float mrow[4], lrow[4];
#pragma unroll
    for (int i = 0; i < 4; ++i) { mrow[i] = -1e38f; lrow[i] = 0.f; }
    int t0 = g >= 4 ? g - 4 : 0;
    int tid = threadIdx.x;
    int kr = tid >> 2, kc = (tid & 3) * 32;
    int vr = tid >> 1, vc = (tid & 1) * 32;
    for (int t = t0; t <= g; ++t) {
        __syncthreads();
        {
            const u16* kg = &k[kvbase + (size_t)(t * 64 + kr) * HD_ + kc];
#pragma unroll
            for (int i = 0; i < 4; ++i)
                *(uint4*)&Ks[kr][kc + i * 8] = *(const uint4*)&kg[i * 8];
            const u16* vg = &vt[vtbase + (size_t)vr * S_ + t * 64 + vc];
#pragma unroll
            for (int i = 0; i < 4; ++i)
                *(uint4*)&Vts[vr][vc + i * 8] = *(const uint4*)&vg[i * 8];
        }
        __syncthreads();
        // S = Q K^T  (4 key-subtiles x 4 k-chunks)
        f32x4 sacc[4] = {};
#pragma unroll
        for (int ks = 0; ks < 4; ++ks)
#pragma unroll
            for (int kb = 0; kb < 4; ++kb) {
                bf16x8 bf = *(const bf16x8*)&Ks[ks * 16 + col16][kb * 32 + quad * 8];
                sacc[ks] = __builtin_amdgcn_mfma_f32_16x16x32_bf16(af[kb], bf, sacc[ks], 0, 0, 0);
            }
        // mask + scale + online softmax (per query row = quad*4+i)
        float pm[4][4];
        float tmax[4] = {-3e38f, -3e38f, -3e38f, -3e38f};
#pragma unroll
        for (int ks = 0; ks < 4; ++ks) {
            int jg = t * 64 + ks * 16 + col16;
#pragma unroll
            for (int i = 0; i < 4; ++i) {
                int qi = q0w + quad * 4 + i;
                bool valid = (jg <= qi) && (qi - jg < WIN_);
                float sv = valid ? sacc[ks][i] * SCALE_ : -3e38f;
                pm[ks][i] = sv;
                tmax[i] = fmaxf(tmax[i], sv);
            }
        }
#pragma unroll
        for (int off = 8; off >= 1; off >>= 1)
#pragma unroll
            for (int i = 0; i < 4; ++i)
                tmax[i] = fmaxf(tmax[i], __shfl_xor(tmax[i], off));
        float alpha[4], psum[4];
#pragma unroll
        for (int i = 0; i < 4; ++i) {
            float mnew = fmaxf(mrow[i], tmax[i]);
            alpha[i] = __expf(mrow[i] - mnew);
            mrow[i] = mnew;
            psum[i] = 0.f;
        }
#pragma unroll
        for (int ks = 0; ks < 4; ++ks)
#pragma unroll
            for (int i = 0; i < 4; ++i) {
                float p = __expf(pm[ks][i] - mrow[i]);
                psum[i] += p;
                Ps[w][quad * 4 + i][ks * 16 + col16] = f2b(p);
            }
#pragma unroll
        for (int off = 8; off >= 1; off >>= 1)
#pragma unroll
            for (int i = 0; i < 4; ++i)
                psum[i] += __shfl_xor(psum[i], off);
#pragma unroll
        for (int i = 0; i < 4; ++i)
            lrow[i] = lrow[i] * alpha[i] + psum[i];
#pragma unroll
        for (int ns = 0; ns < 8; ++ns)
#pragma unroll
            for (int i = 0; i < 4; ++i)
                oacc[ns][i] *= alpha[i];
        // PV: O[16q x 128d] += P[16q x 64k] @ V[64k x 128d]
#pragma unroll
        for (int c = 0; c < 2; ++c) {
            bf16x8 pf = *(const bf16x8*)&Ps[w][col16][c * 32 + quad * 8];
#pragma unroll
            for (int ns = 0; ns < 8; ++ns) {
                bf16x8 vf = *(const bf16x8*)&Vts[ns * 16 + col16][c * 32 + quad * 8];
                oacc[ns] = __builtin_amdgcn_mfma_f32_16x16x32_bf16(pf, vf, oacc[ns], 0, 0, 0);
            }
        }
    }
    int b = bh >> 4, hh = bh & 15;
#pragma unroll
    for (int i = 0; i < 4; ++i) {
        int qi = q0w + quad * 4 + i;
        float invl = 1.f / lrow[i];
        size_t ob = (size_t)(b * S_ + qi) * D_ + hh * HD_;
#pragma unroll
        for (int ns = 0; ns < 8; ++ns)
            y[ob + ns * 16 + col16] = f2b(oacc[ns][i] * invl);
    }
}

// ---------------------------- host orchestration ---------------------------
extern "C" void kernel_launch(void* const* d_in, const int* in_sizes, int n_in,
                              void* d_out, int out_size, void* d_ws, size_t ws_size,
                              hipStream_t stream) {
    const float* x      = (const float*)d_in[0];
    const float* freqs  = (const float*)d_in[1];
    // d_in[2] = mask (unused; computed analytically)
    const float* wqkv_w = (const float*)d_in[3];
    const float* wqkv_b = (const float*)d_in[4];
    const float* wo_w   = (const float*)d_in[5];
    const float* wo_b   = (const float*)d_in[6];
    const float* qn_w   = (const float*)d_in[7];
    const float* kn_w   = (const float*)d_in[8];
    const float* aln_w  = (const float*)d_in[9];
    const float* aln_b  = (const float*)d_in[10];
    const float* fln_w  = (const float*)d_in[11];
    const float* fln_b  = (const float*)d_in[12];
    const float* w1_w   = (const float*)d_in[13];
    const float* w1_b   = (const float*)d_in[14];
    const float* w2_w   = (const float*)d_in[15];
    const float* w2_b   = (const float*)d_in[16];
    float* out = (float*)d_out;

    char* ws = (char*)d_ws;
    size_t off = 0;
    auto alloc = [&](size_t bytes) { char* p = ws + off; off += (bytes + 255) & ~(size_t)255; return (u16*)p; };
    const size_t E = sizeof(u16);
    u16* wt_qkv = alloc((size_t)D_ * 3 * D_ * E);       // bf16 [6144,2048]
    u16* wt_wo  = alloc((size_t)D_ * D_ * E);           // bf16 [2048,2048]
    u16* wt_w1  = alloc((size_t)D_ * FF_ * E);          // bf16 [4096,2048]
    u16* wt_w2  = alloc((size_t)FF_ * D_ * E);          // bf16 [2048,4096]
    u16* nx     = alloc((size_t)B_ * S_ * D_ * E);      // bf16; reused as y
    u16* f      = alloc((size_t)B_ * S_ * D_ * E);      // bf16
    u16* qkv    = alloc((size_t)B_ * S_ * 3 * D_ * E);  // bf16; reused as tmid
    u16* qb     = alloc((size_t)B_ * S_ * D_ * E);      // bf16 [b][h][s][d]
    u16* kb     = alloc((size_t)B_ * S_ * D_ * E);      // bf16 [b][h][s][d]
    u16* vtb    = alloc((size_t)B_ * S_ * D_ * E);      // bf16 [b][h][d][s]
    u16* y    = nx;    // nx consumed by QKV GEMM before attention writes y
    u16* tmid = qkv;   // qkv consumed by qk_rope/v_transpose before FFN1
    float* h  = out;   // h lives in d_out

    if (off > ws_size) return;  // tripwire -> finite err signature

    const int M = B_ * S_;  // 4096

    transpose_k<<<dim3(3 * D_ / 32, D_ / 32), 256, 0, stream>>>(wqkv_w, wt_qkv, D_, 3 * D_);
    transpose_k<<<dim3(D_ / 32, D_ / 32),     256, 0, stream>>>(wo_w,   wt_wo,  D_, D_);
    transpose_k<<<dim3(FF_ / 32, D_ / 32),    256, 0, stream>>>(w1_w,   wt_w1,  D_, FF_);
    transpose_k<<<dim3(D_ / 32, FF_ / 32),    256, 0, stream>>>(w2_w,   wt_w2,  FF_, D_);

    ln_dual<<<M, 256, 0, stream>>>(x, aln_w, aln_b, fln_w, fln_b, nx, f);

    gemm_bt<0><<<dim3(3 * D_ / 128, M / 128), 256, 0, stream>>>(nx, wt_qkv, wqkv_b, nullptr, qkv, M, 3 * D_, D_);

    qk_rope<<<B_ * S_ * H_ / 4, 256, 0, stream>>>(qkv, qn_w, kn_w, freqs, qb, kb);
    v_transpose<<<dim3(S_ / 64, HD_ / 32, B_ * H_), 256, 0, stream>>>((const u32*)qkv, (u32*)vtb);

    attn_mfma<<<B_ * H_ * (S_ / 64), 256, 0, stream>>>(qb, kb, vtb, y);

    // FFN1 first so f is consumed; then WO writes h = out.
    gemm_bt<2><<<dim3(FF_ / 128, M / 128), 256, 0, stream>>>(f, wt_w1, w1_b, nullptr, tmid, M, FF_, D_);

    gemm_bt<1><<<dim3(D_ / 128, M / 128), 256, 0, stream>>>(y, wt_wo, wo_b, x, h, M, D_, D_);

    gemm_bt<1><<<dim3(D_ / 128, M / 128), 256, 0, stream>>>(tmid, wt_w2, w2_b, h, out, M, D_, FF_);
}

// Round 6
// 696.458 us; speedup vs baseline: 1.4935x; 1.0258x over previous
//
#include <hip/hip_runtime.h>

// TransformerBlock on MI355X (gfx950). External dtype: FP32. Internals bf16.
//   transpose_k: W fp32 [R][C] -> bf16 [C][R]  (64x64 tiles, u32 stores)
//   ln_dual:     nx = LN(x,attn_ln), f = LN(x,ffn_ln)
//   gemm<0>:     qkv = nx @ Wqkv + b          (m97 structure: global_load_lds)
//   qk_rope:     RMSNorm + RoPE(first 32 dims) on q,k   (u32-vectorized)
//   v_transpose: V part of qkv -> vt [b][h][dim][key]
//   attn_mfma:   sliding-window(256) causal flash attention, MFMA
//   gemm<2>:     tmid = gelu_exact(f @ W1 + b1)
//   gemm<1>:     h = x + y @ Wo + b           (fp32, in d_out)
//   gemm<1>:     out = h + tmid @ W2 + b2
//
// R5 -> R6: gemm staging moved to __builtin_amdgcn_global_load_lds width=16
// with UNPADDED [128][32] LDS tiles (guide m93->m97: 517->874 TF; the LDS
// dest is wave-uniform base + lane*16, so padding is illegal). Weight
// transpose re-tiled 64x64 with paired-row u32 stores. qk_rope u32-ized.

typedef unsigned short u16;
typedef unsigned int   u32;
typedef __bf16 bf16x8 __attribute__((ext_vector_type(8)));
typedef float  f32x4  __attribute__((ext_vector_type(4)));
typedef __attribute__((address_space(3))) u32 as3_u32;
typedef __attribute__((address_space(1))) u32 as1_u32;

#define B_    2
#define S_    2048
#define D_    2048
#define H_    16
#define HD_   128
#define FF_   4096
#define WIN_  256
#define EPS_  1e-5f
#define SCALE_ 0.08838834764831845f  // 1/sqrt(128)

__device__ __forceinline__ float b2f(u16 u) {
    return __uint_as_float(((u32)u) << 16);
}
__device__ __forceinline__ u16 f2b(float f) {
    u32 u = __float_as_uint(f);
    u32 r = (u + 0x7fffu + ((u >> 16) & 1u)) >> 16;  // RNE
    return (u16)r;
}
__device__ __forceinline__ float wave_sum(float v) {
#pragma unroll
    for (int o = 32; o > 0; o >>= 1) v += __shfl_xor(v, o);
    return v;
}
// async 16B/lane global->LDS; lds base must be wave-uniform, lane i lands at
// base + i*16 (m97 pattern).
__device__ __forceinline__ void gld_lds16(const u16* g, u16* l) {
    __builtin_amdgcn_global_load_lds((const as1_u32*)g, (as3_u32*)l, 16, 0, 0);
}

// -------- weight transpose + cast: in fp32 [R][C] -> out bf16 [C][R] -------
// 64x64 tile; write phase packs row-pairs into u32 (contiguous along R).
__global__ __launch_bounds__(256) void transpose_k(const float* __restrict__ in,
                                                   u16* __restrict__ out,
                                                   int R, int C) {
    __shared__ float tile[64][65];
    int t = threadIdx.x;
    int r0 = blockIdx.y * 64, c0 = blockIdx.x * 64;
    int rr = t >> 2;              // 0..63
    int cb = (t & 3) * 16;        // 0,16,32,48
    const float* src = &in[(size_t)(r0 + rr) * C + c0 + cb];
#pragma unroll
    for (int j = 0; j < 16; j += 4) {
        float4 v = *(const float4*)&src[j];
        tile[rr][cb + j]     = v.x; tile[rr][cb + j + 1] = v.y;
        tile[rr][cb + j + 2] = v.z; tile[rr][cb + j + 3] = v.w;
    }
    __syncthreads();
    int wq = t & 31;              // row-pair 0..31 (rows 2wq, 2wq+1)
    int ch = t >> 5;              // 0..7
#pragma unroll
    for (int i = 0; i < 8; ++i) {
        int c = ch * 8 + i;       // 0..63
        u32 lo = (u32)f2b(tile[2 * wq][c]);
        u32 hi = (u32)f2b(tile[2 * wq + 1][c]);
        ((u32*)out)[(((size_t)(c0 + c) * R) >> 1) + (r0 >> 1) + wq] = lo | (hi << 16);
    }
}

// ---------- dual LayerNorm: fp32 x -> bf16 nx, f (one pass) ----------------
__global__ __launch_bounds__(256) void ln_dual(const float* __restrict__ x,
        const float* __restrict__ aw, const float* __restrict__ ab,
        const float* __restrict__ fw, const float* __restrict__ fb,
        u16* __restrict__ nx, u16* __restrict__ f) {
    int row = blockIdx.x;                // 0..B*S-1
    const float* xr = x + (size_t)row * D_;
    int base = threadIdx.x * 8;
    float4 xa = *(const float4*)&xr[base];
    float4 xb = *(const float4*)&xr[base + 4];
    float xv[8] = {xa.x, xa.y, xa.z, xa.w, xb.x, xb.y, xb.z, xb.w};
    float s = 0.f, s2 = 0.f;
#pragma unroll
    for (int i = 0; i < 8; ++i) { s += xv[i]; s2 += xv[i] * xv[i]; }
    s = wave_sum(s); s2 = wave_sum(s2);
    __shared__ float r1[4], r2[4];
    int w = threadIdx.x >> 6;
    if ((threadIdx.x & 63) == 0) { r1[w] = s; r2[w] = s2; }
    __syncthreads();
    float ts  = r1[0] + r1[1] + r1[2] + r1[3];
    float ts2 = r2[0] + r2[1] + r2[2] + r2[3];
    float mean = ts * (1.f / D_);
    float var  = ts2 * (1.f / D_) - mean * mean;
    float inv  = rsqrtf(var + EPS_);
    float4 wa0 = *(const float4*)&aw[base], wa1 = *(const float4*)&aw[base + 4];
    float4 ba0 = *(const float4*)&ab[base], ba1 = *(const float4*)&ab[base + 4];
    float4 wf0 = *(const float4*)&fw[base], wf1 = *(const float4*)&fw[base + 4];
    float4 bf0 = *(const float4*)&fb[base], bf1 = *(const float4*)&fb[base + 4];
    float wav[8] = {wa0.x, wa0.y, wa0.z, wa0.w, wa1.x, wa1.y, wa1.z, wa1.w};
    float bav[8] = {ba0.x, ba0.y, ba0.z, ba0.w, ba1.x, ba1.y, ba1.z, ba1.w};
    float wfv[8] = {wf0.x, wf0.y, wf0.z, wf0.w, wf1.x, wf1.y, wf1.z, wf1.w};
    float bfv[8] = {bf0.x, bf0.y, bf0.z, bf0.w, bf1.x, bf1.y, bf1.z, bf1.w};
    union { uint4 v; u16 s[8]; } o1, o2;
#pragma unroll
    for (int i = 0; i < 8; ++i) {
        float t = (xv[i] - mean) * inv;
        o1.s[i] = f2b(t * wav[i] + bav[i]);
        o2.s[i] = f2b(t * wfv[i] + bfv[i]);
    }
    *(uint4*)&nx[(size_t)row * D_ + base] = o1.v;
    *(uint4*)&f [(size_t)row * D_ + base] = o2.v;
}

// ---------------- MFMA GEMM: C[M,N] = A[M,K] @ BT[N,K]^T + bias ------------
// m97 structure: unpadded [128][32] LDS tiles, global_load_lds width=16.
// EPI 0: bf16 out.  EPI 1: fp32 out, += fp32 residual.  EPI 2: bf16 out, GELU.
template <int EPI>
__global__ __launch_bounds__(256, 2) void gemm_bt(
        const u16* __restrict__ A, const u16* __restrict__ BT,
        const float* __restrict__ bias, const float* __restrict__ res,
        void* __restrict__ Cv, int M, int N, int K) {
    __shared__ __align__(16) u16 As[128][32];
    __shared__ __align__(16) u16 Bs[128][32];
    int m0 = blockIdx.y * 128, n0 = blockIdx.x * 128;
    int w = threadIdx.x >> 6, lane = threadIdx.x & 63;
    int wm = (w >> 1) * 64, wn = (w & 1) * 64;
    int row16 = lane & 15, quad = lane >> 4;
    int lr = lane >> 2;            // staging row within 16-row group
    int lc = (lane & 3) * 8;       // staging col (u16 units): 0,8,16,24
    f32x4 acc[4][4] = {};
    for (int k0 = 0; k0 < K; k0 += 32) {
        __syncthreads();
        // wave w stages rows [j*64 + w*16, +16) of each 128-row tile
        gld_lds16(&A [(size_t)(m0 +      w * 16 + lr) * K + k0 + lc], &As[     w * 16][0]);
        gld_lds16(&A [(size_t)(m0 + 64 + w * 16 + lr) * K + k0 + lc], &As[64 + w * 16][0]);
        gld_lds16(&BT[(size_t)(n0 +      w * 16 + lr) * K + k0 + lc], &Bs[     w * 16][0]);
        gld_lds16(&BT[(size_t)(n0 + 64 + w * 16 + lr) * K + k0 + lc], &Bs[64 + w * 16][0]);
        __syncthreads();
        bf16x8 af[4], bfr[4];
#pragma unroll
        for (int i = 0; i < 4; ++i) {
            af[i]  = *(const bf16x8*)&As[wm + i * 16 + row16][quad * 8];
            bfr[i] = *(const bf16x8*)&Bs[wn + i * 16 + row16][quad * 8];
        }
#pragma unroll
        for (int mi = 0; mi < 4; ++mi)
#pragma unroll
            for (int ni = 0; ni < 4; ++ni)
                acc[mi][ni] = __builtin_amdgcn_mfma_f32_16x16x32_bf16(
                        af[mi], bfr[ni], acc[mi][ni], 0, 0, 0);
    }
#pragma unroll
    for (int mi = 0; mi < 4; ++mi) {
#pragma unroll
        for (int ni = 0; ni < 4; ++ni) {
            int gcol = n0 + wn + ni * 16 + row16;
            float bv = bias[gcol];
#pragma unroll
            for (int i = 0; i < 4; ++i) {
                int grow = m0 + wm + mi * 16 + quad * 4 + i;
                float vv = acc[mi][ni][i] + bv;
                if (EPI == 1) {
                    vv += res[(size_t)grow * N + gcol];
                    ((float*)Cv)[(size_t)grow * N + gcol] = vv;
                } else {
                    if (EPI == 2)
                        vv = vv * 0.5f * (1.0f + erff(vv * 0.70710678118654752f));
                    ((u16*)Cv)[(size_t)grow * N + gcol] = f2b(vv);
                }
            }
        }
    }
}

// ---------------- QK RMSNorm + partial RoPE (q,k only), u32-vectorized -----
// One wave per (b,s,h). Lane l holds dims (2l, 2l+1) as one u32.
// RoPE: out[2j]=x0[j]c-x1[j]s, out[2j+1]=x1[j]c+x0[j]s, x0[j]=dim j,
// x1[j]=dim 16+j  -> lanes 0..15 produce their pair via 4 shuffles.
__global__ __launch_bounds__(256) void qk_rope(const u32* __restrict__ qkv32,
        const float* __restrict__ qn_w, const float* __restrict__ kn_w,
        const float* __restrict__ freqs,
        u32* __restrict__ q32, u32* __restrict__ k32) {
    int w = threadIdx.x >> 6, lane = threadIdx.x & 63;
    int unit = blockIdx.x * 4 + w;           // b*S*H + s*H + h
    int h = unit & (H_ - 1);
    int s = (unit >> 4) & (S_ - 1);
    int b = unit >> 15;
    size_t inbase  = (size_t)(b * S_ + s) * (3 * D_ / 2) + h * (HD_ / 2);
    size_t outbase = ((size_t)((b * H_ + h) * S_) + s) * (HD_ / 2);
    float fc = 0.f, fs = 0.f;
    if (lane < 16) {
        fc = freqs[(s * 16 + lane) * 2];
        fs = freqs[(s * 16 + lane) * 2 + 1];
    }
#pragma unroll
    for (int part = 0; part < 2; ++part) {   // 0: q, 1: k
        const float* nw = part ? kn_w : qn_w;
        u32 wv = qkv32[inbase + part * (D_ / 2) + lane];
        float a0 = b2f((u16)(wv & 0xffffu));
        float a1 = b2f((u16)(wv >> 16));
        float ss = wave_sum(a0 * a0 + a1 * a1);
        float inv = rsqrtf(ss * (1.f / HD_) + EPS_);
        float2 nwp = *(const float2*)&nw[2 * lane];
        float n0 = a0 * inv * nwp.x;
        float n1 = a1 * inv * nwp.y;
        // gather x0[j]=dim j (lane j>>1, parity j&1), x1[j]=dim 16+j
        float e0 = __shfl(n0, lane >> 1), e1 = __shfl(n1, lane >> 1);
        float o0 = __shfl(n0, 8 + (lane >> 1)), o1 = __shfl(n1, 8 + (lane >> 1));
        float x0 = (lane & 1) ? e1 : e0;
        float x1 = (lane & 1) ? o1 : o0;
        float rv0 = x0 * fc - x1 * fs;
        float rv1 = x1 * fc + x0 * fs;
        float w0 = (lane < 16) ? rv0 : n0;
        float w1 = (lane < 16) ? rv1 : n1;
        u32* dst = part ? k32 : q32;
        dst[outbase + lane] = (u32)f2b(w0) | ((u32)f2b(w1) << 16);
    }
}

// -------- V transpose: qkv V-part [b][s][h][d] -> vt [b][h][d][s] ----------
__global__ __launch_bounds__(256) void v_transpose(const u32* __restrict__ qkv32,
                                                   u32* __restrict__ vt32) {
    __shared__ u32 tile[64][17];
    int bh = blockIdx.z; int b = bh >> 4, h = bh & 15;
    int s0 = blockIdx.x * 64, d0 = blockIdx.y * 32;
    int tid = threadIdx.x;
    int rr = tid >> 4, cc = tid & 15;          // rr 0..15, cc 0..15 (u32 cols)
#pragma unroll
    for (int i = 0; i < 4; ++i) {
        int s = s0 + rr + i * 16;
        tile[rr + i * 16][cc] =
            qkv32[(size_t)(b * S_ + s) * (3 * D_ / 2) + (2 * D_ + h * HD_ + d0) / 2 + cc];
    }
    __syncthreads();
    int dr = tid & 31, sc = tid >> 5;          // dr 0..31, sc 0..7
#pragma unroll
    for (int i = 0; i < 4; ++i) {
        int s2 = sc + i * 8;                   // s-pair index 0..31
        u32 w0 = tile[2 * s2][dr >> 1];
        u32 w1 = tile[2 * s2 + 1][dr >> 1];
        u32 h0 = (dr & 1) ? (w0 >> 16) : (w0 & 0xffffu);
        u32 h1 = (dr & 1) ? (w1 >> 16) : (w1 & 0xffffu);
        vt32[((size_t)bh * HD_ + d0 + dr) * (S_ / 2) + (s0 >> 1) + s2] = h0 | (h1 << 16);
    }
}

// ---------------- MFMA sliding-window causal flash attention ---------------
__global__ __launch_bounds__(256) void attn_mfma(
        const u16* __restrict__ q, const u16* __restrict__ k,
        const u16* __restrict__ vt, u16* __restrict__ y) {
    __shared__ __align__(16) u16 Ks [64][136];   // 272B rows: 68-word stride
    __shared__ __align__(16) u16 Vts[128][72];   // 144B rows: 36-word stride
    __shared__ __align__(16) u16 Ps [4][16][72];
    int g  = blockIdx.x & (S_ / 64 - 1);   // 0..31
    int bh = blockIdx.x >> 5;              // 0..31
    int qbase = g * 64;
    size_t kvbase = (size_t)bh * S_ * HD_;
    size_t vtbase = (size_t)bh * HD_ * S_;
    int w = threadIdx.x >> 6, lane = threadIdx.x & 63;
    int col16 = lane & 15, quad = lane >> 4;
    int q0w = qbase + w * 16;
    bf16x8 af[4];
#pragma unroll
    for (int kb = 0; kb < 4; ++kb)
        af[kb] = *(const bf16x8*)&q[kvbase + (size_t)(q0w + col16) * HD_ + kb * 32 + quad * 8];
    f32x4 oacc[8] = {};
    float mrow[4], lrow[4];
#pragma unroll
    for (int i = 0; i < 4; ++i) { mrow[i] = -1e38f; lrow[i] = 0.f; }
    int t0 = g >= 4 ? g - 4 : 0;
    int tid = threadIdx.x;
    int kr = tid >> 2, kc = (tid & 3) * 32;
    int vr = tid >> 1, vc = (tid & 1) * 32;
    for (int t = t0; t <= g; ++t) {
        __syncthreads();
        {
            const u16* kg = &k[kvbase + (size_t)(t * 64 + kr) * HD_ + kc];
#pragma unroll
            for (int i = 0; i < 4; ++i)
                *(uint4*)&Ks[kr][kc + i * 8] = *(const uint4*)&kg[i * 8];
            const u16* vg = &vt[vtbase + (size_t)vr * S_ + t * 64 + vc];
#pragma unroll
            for (int i = 0; i < 4; ++i)
                *(uint4*)&Vts[vr][vc + i * 8] = *(const uint4*)&vg[i * 8];
        }
        __syncthreads();
        f32x4 sacc[4] = {};
#pragma unroll
        for (int ks = 0; ks < 4; ++ks)
#pragma unroll
            for (int kb = 0; kb < 4; ++kb) {
                bf16x8 bf = *(const bf16x8*)&Ks[ks * 16 + col16][kb * 32 + quad * 8];
                sacc[ks] = __builtin_amdgcn_mfma_f32_16x16x32_bf16(af[kb], bf, sacc[ks], 0, 0, 0);
            }
        float pm[4][4];
        float tmax[4] = {-3e38f, -3e38f, -3e38f, -3e38f};
#pragma unroll
        for (int ks = 0; ks < 4; ++ks) {
            int jg = t * 64 + ks * 16 + col16;
#pragma unroll
            for (int i = 0; i < 4; ++i) {
                int qi = q0w + quad * 4 + i;
                bool valid = (jg <= qi) && (qi - jg < WIN_);
                float sv = valid ? sacc[ks][i] * SCALE_ : -3e38f;
                pm[ks][i] = sv;
                tmax[i] = fmaxf(tmax[i], sv);
            }
        }
#pragma unroll
        for (int off = 8; off >= 1; off >>= 1)
#pragma unroll
            for (int i = 0; i < 4; ++i)
                tmax[i] = fmaxf(tmax[i], __shfl_xor(tmax[i], off));
        float alpha[4], psum[4];
#pragma unroll
        for (int i = 0; i < 4; ++i) {
            float mnew = fmaxf(mrow[i], tmax[i]);
            alpha[i] = __expf(mrow[i] - mnew);
            mrow[i] = mnew;
            psum[i] = 0.f;
        }
#pragma unroll
        for (int ks = 0; ks < 4; ++ks)
#pragma unroll
            for (int i = 0; i < 4; ++i) {
                float p = __expf(pm[ks][i] - mrow[i]);
                psum[i] += p;
                Ps[w][quad * 4 + i][ks * 16 + col16] = f2b(p);
            }
#pragma unroll
        for (int off = 8; off >= 1; off >>= 1)
#pragma unroll
            for (int i = 0; i < 4; ++i)
                psum[i] += __shfl_xor(psum[i], off);
#pragma unroll
        for (int i = 0; i < 4; ++i)
            lrow[i] = lrow[i] * alpha[i] + psum[i];
#pragma unroll
        for (int ns = 0; ns < 8; ++ns)
#pragma unroll
            for (int i = 0; i < 4; ++i)
                oacc[ns][i] *= alpha[i];
#pragma unroll
        for (int c = 0; c < 2; ++c) {
            bf16x8 pf = *(const bf16x8*)&Ps[w][col16][c * 32 + quad * 8];
#pragma unroll
            for (int ns = 0; ns < 8; ++ns) {
                bf16x8 vf = *(const bf16x8*)&Vts[ns * 16 + col16][c * 32 + quad * 8];
                oacc[ns] = __builtin_amdgcn_mfma_f32_16x16x32_bf16(pf, vf, oacc[ns], 0, 0, 0);
            }
        }
    }
    int b = bh >> 4, hh = bh & 15;
#pragma unroll
    for (int i = 0; i < 4; ++i) {
        int qi = q0w + quad * 4 + i;
        float invl = 1.f / lrow[i];
        size_t ob = (size_t)(b * S_ + qi) * D_ + hh * HD_;
#pragma unroll
        for (int ns = 0; ns < 8; ++ns)
            y[ob + ns * 16 + col16] = f2b(oacc[ns][i] * invl);
    }
}

// ---------------------------- host orchestration ---------------------------
extern "C" void kernel_launch(void* const* d_in, const int* in_sizes, int n_in,
                              void* d_out, int out_size, void* d_ws, size_t ws_size,
                              hipStream_t stream) {
    const float* x      = (const float*)d_in[0];
    const float* freqs  = (const float*)d_in[1];
    // d_in[2] = mask (unused; computed analytically)
    const float* wqkv_w = (const float*)d_in[3];
    const float* wqkv_b = (const float*)d_in[4];
    const float* wo_w   = (const float*)d_in[5];
    const float* wo_b   = (const float*)d_in[6];
    const float* qn_w   = (const float*)d_in[7];
    const float* kn_w   = (const float*)d_in[8];
    const float* aln_w  = (const float*)d_in[9];
    const float* aln_b  = (const float*)d_in[10];
    const float* fln_w  = (const float*)d_in[11];
    const float* fln_b  = (const float*)d_in[12];
    const float* w1_w   = (const float*)d_in[13];
    const float* w1_b   = (const float*)d_in[14];
    const float* w2_w   = (const float*)d_in[15];
    const float* w2_b   = (const float*)d_in[16];
    float* out = (float*)d_out;

    char* ws = (char*)d_ws;
    size_t off = 0;
    auto alloc = [&](size_t bytes) { char* p = ws + off; off += (bytes + 255) & ~(size_t)255; return (u16*)p; };
    const size_t E = sizeof(u16);
    u16* wt_qkv = alloc((size_t)D_ * 3 * D_ * E);       // bf16 [6144,2048]
    u16* wt_wo  = alloc((size_t)D_ * D_ * E);           // bf16 [2048,2048]
    u16* wt_w1  = alloc((size_t)D_ * FF_ * E);          // bf16 [4096,2048]
    u16* wt_w2  = alloc((size_t)FF_ * D_ * E);          // bf16 [2048,4096]
    u16* nx     = alloc((size_t)B_ * S_ * D_ * E);      // bf16; reused as y
    u16* f      = alloc((size_t)B_ * S_ * D_ * E);      // bf16
    u16* qkv    = alloc((size_t)B_ * S_ * 3 * D_ * E);  // bf16; reused as tmid
    u16* qb     = alloc((size_t)B_ * S_ * D_ * E);      // bf16 [b][h][s][d]
    u16* kb     = alloc((size_t)B_ * S_ * D_ * E);      // bf16 [b][h][s][d]
    u16* vtb    = alloc((size_t)B_ * S_ * D_ * E);      // bf16 [b][h][d][s]
    u16* y    = nx;    // nx consumed by QKV GEMM before attention writes y
    u16* tmid = qkv;   // qkv consumed by qk_rope/v_transpose before FFN1
    float* h  = out;   // h lives in d_out

    if (off > ws_size) return;  // tripwire -> finite err signature

    const int M = B_ * S_;  // 4096

    transpose_k<<<dim3(3 * D_ / 64, D_ / 64), 256, 0, stream>>>(wqkv_w, wt_qkv, D_, 3 * D_);
    transpose_k<<<dim3(D_ / 64, D_ / 64),     256, 0, stream>>>(wo_w,   wt_wo,  D_, D_);
    transpose_k<<<dim3(FF_ / 64, D_ / 64),    256, 0, stream>>>(w1_w,   wt_w1,  D_, FF_);
    transpose_k<<<dim3(D_ / 64, FF_ / 64),    256, 0, stream>>>(w2_w,   wt_w2,  FF_, D_);

    ln_dual<<<M, 256, 0, stream>>>(x, aln_w, aln_b, fln_w, fln_b, nx, f);

    gemm_bt<0><<<dim3(3 * D_ / 128, M / 128), 256, 0, stream>>>(nx, wt_qkv, wqkv_b, nullptr, qkv, M, 3 * D_, D_);

    qk_rope<<<B_ * S_ * H_ / 4, 256, 0, stream>>>((const u32*)qkv, qn_w, kn_w, freqs, (u32*)qb, (u32*)kb);
    v_transpose<<<dim3(S_ / 64, HD_ / 32, B_ * H_), 256, 0, stream>>>((const u32*)qkv, (u32*)vtb);

    attn_mfma<<<B_ * H_ * (S_ / 64), 256, 0, stream>>>(qb, kb, vtb, y);

    // FFN1 first so f is consumed; then WO writes h = out.
    gemm_bt<2><<<dim3(FF_ / 128, M / 128), 256, 0, stream>>>(f, wt_w1, w1_b, nullptr, tmid, M, FF_, D_);

    gemm_bt<1><<<dim3(D_ / 128, M / 128), 256, 0, stream>>>(y, wt_wo, wo_b, x, h, M, D_, D_);

    gemm_bt<1><<<dim3(D_ / 128, M / 128), 256, 0, stream>>>(tmid, wt_w2, w2_b, h, out, M, D_, FF_);
}